// Round 2
// baseline (1069.329 us; speedup 1.0000x reference)
//
#include <hip/hip_runtime.h>
#include <math.h>

// Problem constants (B,S,H fixed by reference setup_inputs)
#define BB 32
#define SS 4096
#define HH 1024
#define NCHUNK 64               // grid 64*32 = 2048 blocks
#define CHUNK (SS / NCHUNK)     // 64 s-rows per block
#define TILE 4                  // rows per LDS tile (16 KB); one row per wave
#define NT (CHUNK / TILE)       // 16 tiles
#define NEG_INF9 (-1.0e9f)

// ---------------------------------------------------------------------------
// Wave64 all-reduce(sum) via DPP tree; result broadcast via readlane (SGPR).
// ---------------------------------------------------------------------------
__device__ __forceinline__ float dpp_allreduce_add(float x) {
    int t;
    t = __builtin_amdgcn_update_dpp(0, __float_as_int(x), 0x111, 0xf, 0xf, false); // row_shr:1
    x += __int_as_float(t);
    t = __builtin_amdgcn_update_dpp(0, __float_as_int(x), 0x112, 0xf, 0xf, false); // row_shr:2
    x += __int_as_float(t);
    t = __builtin_amdgcn_update_dpp(0, __float_as_int(x), 0x114, 0xf, 0xf, false); // row_shr:4
    x += __int_as_float(t);
    t = __builtin_amdgcn_update_dpp(0, __float_as_int(x), 0x118, 0xf, 0xf, false); // row_shr:8
    x += __int_as_float(t);
    t = __builtin_amdgcn_update_dpp(0, __float_as_int(x), 0x142, 0xf, 0xf, false); // row_bcast:15
    x += __int_as_float(t);
    t = __builtin_amdgcn_update_dpp(0, __float_as_int(x), 0x143, 0xf, 0xf, false); // row_bcast:31
    x += __int_as_float(t);
    return __int_as_float(__builtin_amdgcn_readlane(__float_as_int(x), 63));
}

// async global->LDS, 16 B per lane. LDS dest is wave-uniform base + lane*16;
// global src is per-lane (guide §5: m97 pattern, width=16).
__device__ __forceinline__ void gload_lds16(const float* g, void* l) {
    __builtin_amdgcn_global_load_lds((const __attribute__((address_space(1))) void*)g,
                                     (__attribute__((address_space(3))) void*)l, 16, 0, 0);
}

// ---------------- Kernel 1: q = query @ W^T  (+ zero the per-batch done counters) ----------------
__global__ __launch_bounds__(256) void qproj_kernel(const float* __restrict__ query,
                                                    const float* __restrict__ W,
                                                    float* __restrict__ q,
                                                    int* __restrict__ done_cnt) {
    if (blockIdx.x == 0 && blockIdx.y == 0 && threadIdx.x < BB) done_cnt[threadIdx.x] = 0;

    const int b    = blockIdx.y;
    const int wave = threadIdx.x >> 6;
    const int lane = threadIdx.x & 63;

    const float4* qp = (const float4*)(query + (size_t)b * HH);
    float4 qv[4];
#pragma unroll
    for (int r = 0; r < 4; ++r) qv[r] = qp[r * 64 + lane];

    const int obase = blockIdx.x * 64 + wave * 16;
    for (int i = 0; i < 16; ++i) {
        const int o = obase + i;
        const float4* wp = (const float4*)(W + (size_t)o * HH);
        float acc = 0.f;
#pragma unroll
        for (int r = 0; r < 4; ++r) {
            const float4 wv = wp[r * 64 + lane];
            acc += wv.x * qv[r].x + wv.y * qv[r].y + wv.z * qv[r].z + wv.w * qv[r].w;
        }
        const float s = dpp_allreduce_add(acc);
        if (lane == 0) q[(size_t)b * HH + o] = s;
    }
}

// ---------------- Kernel 2: fused scores+softmax+partials + last-block combine ----------------
// Keys are streamed via double-buffered global_load_lds (async DMA, no VGPR round trip):
//   iter t: [__syncthreads: tile t resident] [issue DMA for tile t+1 into other buf] [compute tile t]
// One row per wave per tile; score reduce is DPP -> wave-uniform scalar softmax state.
__global__ __launch_bounds__(256, 4) void attn_fused_kernel(const float* __restrict__ q,
                                                            const float* __restrict__ keys,
                                                            const int* __restrict__ mask,
                                                            float* __restrict__ weights,
                                                            float* __restrict__ pm,
                                                            float* __restrict__ pl,
                                                            float* __restrict__ pO,
                                                            int* __restrict__ done_cnt,
                                                            float* __restrict__ context) {
    const int b    = blockIdx.y;
    const int c    = blockIdx.x;
    const int tid  = threadIdx.x;
    const int wave = tid >> 6;
    const int lane = tid & 63;

    __shared__ __align__(16) char kv_raw[2][TILE * HH * 4];  // 2 x 16 KB key tiles
    __shared__ float sscores[CHUNK];
    __shared__ int   smask[CHUNK];
    __shared__ float sm[4], sl[4];
    __shared__ int   s_last;

    const float4* qp = (const float4*)(q + (size_t)b * HH);
    float4 qv[4];
#pragma unroll
    for (int r = 0; r < 4; ++r) qv[r] = qp[r * 64 + lane];

    if (tid < CHUNK) smask[tid] = mask[(size_t)b * SS + c * CHUNK + tid];

    const float* kchunk = keys + ((size_t)b * SS + (size_t)c * CHUNK) * HH;

    // stage tile tt into dst: 16 pieces of 1 KB; wave w issues pieces {w, w+4, w+8, w+12}
    // LDS layout is linear (byte p*1024), matching the linear global tile.
#define STAGE_TILE(tt, dst)                                                   \
    {                                                                         \
        const float* gbase = kchunk + (size_t)(tt) * TILE * HH;               \
        _Pragma("unroll") for (int j = 0; j < 4; ++j) {                       \
            const int p = j * 4 + wave;                                       \
            gload_lds16(gbase + p * 256 + lane * 4, (char*)(dst) + p * 1024); \
        }                                                                     \
    }

    STAGE_TILE(0, kv_raw[0]);

    float m = -INFINITY;
    float l = 0.f;
    float4 acc[4];
#pragma unroll
    for (int r = 0; r < 4; ++r) acc[r] = make_float4(0.f, 0.f, 0.f, 0.f);

#pragma unroll
    for (int t = 0; t < NT; ++t) {
        __syncthreads();  // tile t fully resident (compiler drains vmcnt before s_barrier)
        if (t + 1 < NT) STAGE_TILE(t + 1, kv_raw[(t + 1) & 1]);  // DMA overlaps compute(t)

        const float4* kt = (const float4*)kv_raw[t & 1];
        float4 kva[4];
#pragma unroll
        for (int r = 0; r < 4; ++r) kva[r] = kt[wave * 256 + r * 64 + lane];

        float x = 0.f;
#pragma unroll
        for (int r = 0; r < 4; ++r)
            x += kva[r].x * qv[r].x + kva[r].y * qv[r].y + kva[r].z * qv[r].z + kva[r].w * qv[r].w;
        float sc = dpp_allreduce_add(x);

        const int rr = t * TILE + wave;
        if (smask[rr] != 0) sc = NEG_INF9;
        if (lane == 0) sscores[rr] = sc;

        if (sc > m) {  // wave-uniform branch; exact (skip <=> scale==1). m=-inf first iter -> scale 0
            const float scale = __expf(m - sc);
            l *= scale;
#pragma unroll
            for (int r = 0; r < 4; ++r) {
                acc[r].x *= scale; acc[r].y *= scale; acc[r].z *= scale; acc[r].w *= scale;
            }
            m = sc;
        }
        const float p = __expf(sc - m);
        l += p;
#pragma unroll
        for (int r = 0; r < 4; ++r) {
            acc[r].x += p * kva[r].x;
            acc[r].y += p * kva[r].y;
            acc[r].z += p * kva[r].z;
            acc[r].w += p * kva[r].w;
        }
    }

    // ---- combine the 4 waves of this block (reuse kv_raw[0] as sO: 16 KB)
    __syncthreads();
    float4* sO = (float4*)kv_raw[0];
#pragma unroll
    for (int r = 0; r < 4; ++r) sO[wave * 256 + r * 64 + lane] = acc[r];
    if (lane == 0) { sm[wave] = m; sl[wave] = l; }
    __syncthreads();

    const float M = fmaxf(fmaxf(sm[0], sm[1]), fmaxf(sm[2], sm[3]));
    float f[4];
#pragma unroll
    for (int w = 0; w < 4; ++w) f[w] = __expf(sm[w] - M);
    const float L = sl[0] * f[0] + sl[1] * f[1] + sl[2] * f[2] + sl[3] * f[3];

    float4 o = make_float4(0.f, 0.f, 0.f, 0.f);
#pragma unroll
    for (int w = 0; w < 4; ++w) {
        const float4 v = sO[w * 256 + tid];
        o.x += f[w] * v.x; o.y += f[w] * v.y; o.z += f[w] * v.z; o.w += f[w] * v.w;
    }
    ((float4*)(pO + ((size_t)b * NCHUNK + c) * HH))[tid] = o;
    if (tid == 0) { pm[b * NCHUNK + c] = M; pl[b * NCHUNK + c] = L; }
    if (tid < CHUNK / 4) {  // flush raw (masked) scores, coalesced
        float4 s4 = make_float4(sscores[tid * 4], sscores[tid * 4 + 1],
                                sscores[tid * 4 + 2], sscores[tid * 4 + 3]);
        ((float4*)(weights + (size_t)b * SS + (size_t)c * CHUNK))[tid] = s4;
    }

    // ---- last-block-per-batch combine (split-K pattern: release fence, count, acquire fence)
    __threadfence();
    __syncthreads();
    if (tid == 0) s_last = (atomicAdd(&done_cnt[b], 1) == NCHUNK - 1);
    __syncthreads();
    if (!s_last) return;
    __threadfence();

    float Mb = -INFINITY;
#pragma unroll 8
    for (int cc = 0; cc < NCHUNK; ++cc) Mb = fmaxf(Mb, pm[b * NCHUNK + cc]);
    float Lb = 0.f;
#pragma unroll 8
    for (int cc = 0; cc < NCHUNK; ++cc) Lb += pl[b * NCHUNK + cc] * __expf(pm[b * NCHUNK + cc] - Mb);
    const float invL = 1.f / Lb;

    const float4* pO4 = (const float4*)pO;
    float4 o2 = make_float4(0.f, 0.f, 0.f, 0.f);
#pragma unroll 8
    for (int cc = 0; cc < NCHUNK; ++cc) {
        const float g = __expf(pm[b * NCHUNK + cc] - Mb) * invL;
        const float4 v = pO4[((size_t)b * NCHUNK + cc) * (HH / 4) + tid];
        o2.x += g * v.x; o2.y += g * v.y; o2.z += g * v.z; o2.w += g * v.w;
    }
    ((float4*)(context + (size_t)b * HH))[tid] = o2;

#pragma unroll
    for (int k = 0; k < SS / 256; ++k) {
        const size_t idx = (size_t)b * SS + k * 256 + tid;
        const float sc = weights[idx];
        weights[idx] = __expf(sc - Mb) * invL;  // masked -1e9 -> exactly 0
    }
}

extern "C" void kernel_launch(void* const* d_in, const int* in_sizes, int n_in,
                              void* d_out, int out_size, void* d_ws, size_t ws_size,
                              hipStream_t stream) {
    const float* query = (const float*)d_in[0];  // [B,1,H]
    const float* keys  = (const float*)d_in[1];  // [B,S,H]
    const int*   mask  = (const int*)d_in[2];    // [B,S] bool->int
    const float* W     = (const float*)d_in[3];  // [H,H]

    float* context = (float*)d_out;                     // B*H floats
    float* weights = (float*)d_out + (size_t)BB * HH;   // B*S floats

    float* q    = (float*)d_ws;                         // B*H
    float* pm   = q + (size_t)BB * HH;                  // B*NCHUNK
    float* pl   = pm + BB * NCHUNK;                     // B*NCHUNK
    float* pO   = pl + BB * NCHUNK;                     // B*NCHUNK*H (8 MB)
    int*   done = (int*)(pO + (size_t)BB * NCHUNK * HH);// B counters

    qproj_kernel<<<dim3(HH / 64, BB), 256, 0, stream>>>(query, W, q, done);
    attn_fused_kernel<<<dim3(NCHUNK, BB), 256, 0, stream>>>(q, keys, mask, weights, pm, pl, pO,
                                                            done, context);
}